// Round 8
// baseline (175.083 us; speedup 1.0000x reference)
//
#include <hip/hip_runtime.h>

#define B_DIM   4096
#define IN_DIM  4096
#define OUT_DIM 4096

typedef float floatx4 __attribute__((ext_vector_type(4)));

// ws[0..4096)    = row sums of input
// ws[4096..8192) = row sums of weight (bias applied later in k2)

__global__ __launch_bounds__(256) void k0_zero(float* __restrict__ ws) {
    ws[blockIdx.x * 256 + threadIdx.x] = 0.f;     // 8192 floats
}

// K1: channel-balanced grid-contiguous read-reduce.
// 2048 blocks x 256 thr = 8192 waves, all co-resident (8 blocks/CU).
// Phase k: the grid reads ONE contiguous 8 MB window; wave w owns the 1 KB
// chunk at offset w*1KB (one float4 per lane). Concurrent wave-loads are
// consecutive 1 KB lines -> every HBM channel is active simultaneously.
// (All previous kernels issued 8-16 KB strided concurrent loads -> channel
// camping -> the 2.8 TB/s read plateau.)
// A wave's row changes each phase, so its 1 KB partial is atomicAdd-ed into
// ws[row]: 16 atomics per row total, spread across the kernel.
__global__ __launch_bounds__(256) void k1_reduce(
    const float* __restrict__ input, const float* __restrict__ weight,
    float* __restrict__ ws)
{
    const int wave = threadIdx.x >> 6;
    const int lane = threadIdx.x & 63;
    const int w    = blockIdx.x * 4 + wave;        // 0 .. 8191
    const int fi   = w * 64 + lane;                // float4 idx in window
    const int rowi = w >> 4;                       // row within window [0,512)

    const floatx4* inp4 = (const floatx4*)input;   // 8 windows of 524288 f4
    const floatx4* wgt4 = (const floatx4*)weight;  // 8 windows

    floatx4 cur = inp4[fi];
    #pragma unroll
    for (int k = 0; k < 16; ++k) {
        floatx4 nxt = cur;                         // prefetch next window
        if (k < 7)        nxt = inp4[(k + 1) * 524288 + fi];
        else if (k < 15)  nxt = wgt4[(k - 7) * 524288 + fi];

        float s = (cur.x + cur.y) + (cur.z + cur.w);
        #pragma unroll
        for (int off = 32; off > 0; off >>= 1)
            s += __shfl_down(s, off, 64);

        if (lane == 0) {
            const int slot = (k < 8) ? (k * 512 + rowi)
                                     : (4096 + (k - 8) * 512 + rowi);
            atomicAdd(&ws[slot], s);
        }
        cur = nxt;
    }
}

// K2: grid-contiguous fused write. 8 phases x contiguous 32 MB windows of
// out; per float4: (xs[b] + wsum[o]) * bias[o] (exactly the ref formula).
// bias/wsum (32 KB) are L1-resident after the first row; xs[b] is ~wave-
// uniform (<=2 rows per wave). Nontemporal stores: out is never re-read.
__global__ __launch_bounds__(256) void k2_write(
    const float* __restrict__ bias, const float* __restrict__ ws,
    float* __restrict__ out)
{
    const int g = blockIdx.x * 256 + threadIdx.x;  // 0 .. 524287
    const floatx4* bias4 = (const floatx4*)bias;
    const floatx4* wsw4  = (const floatx4*)(ws + 4096);
    floatx4* out4 = (floatx4*)out;

    #pragma unroll
    for (int i = 0; i < 8; ++i) {
        const int idx = i * 524288 + g;            // float4 idx into out
        const int b   = idx >> 10;                 // OUT_DIM/4 = 1024
        const int o4  = idx & 1023;

        const float   xs = ws[b];
        const floatx4 bi = bias4[o4];
        const floatx4 wv = wsw4[o4];
        floatx4 r;
        r.x = (xs + wv.x) * bi.x;
        r.y = (xs + wv.y) * bi.y;
        r.z = (xs + wv.z) * bi.z;
        r.w = (xs + wv.w) * bi.w;
        __builtin_nontemporal_store(r, &out4[idx]);
    }
}

extern "C" void kernel_launch(void* const* d_in, const int* in_sizes, int n_in,
                              void* d_out, int out_size, void* d_ws, size_t ws_size,
                              hipStream_t stream) {
    const float* input  = (const float*)d_in[0];
    const float* weight = (const float*)d_in[1];
    const float* bias   = (const float*)d_in[2];
    float* out = (float*)d_out;
    float* ws  = (float*)d_ws;   // 8192 floats of row sums

    k0_zero  <<<32,   256, 0, stream>>>(ws);
    k1_reduce<<<2048, 256, 0, stream>>>(input, weight, ws);
    k2_write <<<2048, 256, 0, stream>>>(bias, ws, out);
}

// Round 9
// 163.806 us; speedup vs baseline: 1.0688x; 1.0688x over previous
//
#include <hip/hip_runtime.h>

#define B_DIM   4096
#define IN_DIM  4096
#define OUT_DIM 4096

typedef float floatx4 __attribute__((ext_vector_type(4)));

// Kernel A: wb[o] = bias[o] * sum_i weight[o,i]. One wave per weight row,
// 4 waves/block, 1024 blocks. Nontemporal loads: weight is streamed once.
// Measured (R5): ~2.85 TB/s effective read — at the machine's load-path
// ceiling (~3 TB/s read-side, cf. m13 copy 6.29 TB/s total = ~3.15 read).
__global__ __launch_bounds__(256) void wsum_kernel(
    const float* __restrict__ weight, const float* __restrict__ bias,
    float* __restrict__ wb)
{
    const int wave = threadIdx.x >> 6;
    const int lane = threadIdx.x & 63;
    const int o    = blockIdx.x * 4 + wave;          // 0 .. 4095

    const floatx4* src4 = (const floatx4*)(weight + (size_t)o * IN_DIM);

    float s0 = 0.f, s1 = 0.f, s2 = 0.f, s3 = 0.f;
    #pragma unroll
    for (int k = 0; k < 16; k += 4) {
        floatx4 v0 = __builtin_nontemporal_load(&src4[lane + (k + 0) * 64]);
        floatx4 v1 = __builtin_nontemporal_load(&src4[lane + (k + 1) * 64]);
        floatx4 v2 = __builtin_nontemporal_load(&src4[lane + (k + 2) * 64]);
        floatx4 v3 = __builtin_nontemporal_load(&src4[lane + (k + 3) * 64]);
        s0 += (v0.x + v0.y) + (v0.z + v0.w);
        s1 += (v1.x + v1.y) + (v1.z + v1.w);
        s2 += (v2.x + v2.y) + (v2.z + v2.w);
        s3 += (v3.x + v3.y) + (v3.z + v3.w);
    }
    float s = (s0 + s1) + (s2 + s3);

    #pragma unroll
    for (int off = 32; off > 0; off >>= 1)
        s += __shfl_down(s, off, 64);

    if (lane == 0)
        wb[o] = s * bias[o];
}

// Kernel B (fused): one block per output row b.
//   phase 1: read input row b (16 KB, nontemporal), block-reduce -> xs
//   phase 2: out[b,:] = xs * bias[:] + wb[:]  (bias/wb 16 KB each,
//            L2-resident), nontemporal stores.
// Across staggered blocks phase-1 reads overlap phase-2 writes, so the
// 64 MiB of writes ride along under the read-path ceiling for free.
__global__ __launch_bounds__(256) void fused_kernel(
    const float* __restrict__ input, const float* __restrict__ bias,
    const float* __restrict__ wb, float* __restrict__ out)
{
    const int b = blockIdx.x;
    const int t = threadIdx.x;

    const floatx4* in4 = (const floatx4*)(input + (size_t)b * IN_DIM);

    floatx4 v[4];
    #pragma unroll
    for (int k = 0; k < 4; ++k)
        v[k] = __builtin_nontemporal_load(&in4[t + k * 256]);

    float s = 0.f;
    #pragma unroll
    for (int k = 0; k < 4; ++k)
        s += (v[k].x + v[k].y) + (v[k].z + v[k].w);

    #pragma unroll
    for (int off = 32; off > 0; off >>= 1)
        s += __shfl_down(s, off, 64);

    __shared__ float sm[4];
    if ((t & 63) == 0) sm[t >> 6] = s;
    __syncthreads();
    const float xs = (sm[0] + sm[1]) + (sm[2] + sm[3]);

    const floatx4* bias4 = (const floatx4*)bias;
    const floatx4* wb4   = (const floatx4*)wb;
    floatx4* out4 = (floatx4*)out + (size_t)b * (OUT_DIM / 4);

    #pragma unroll
    for (int k = 0; k < 4; ++k) {
        const int i = t + k * 256;
        const floatx4 bi = bias4[i];
        const floatx4 w  = wb4[i];
        floatx4 r;
        r.x = fmaf(xs, bi.x, w.x);
        r.y = fmaf(xs, bi.y, w.y);
        r.z = fmaf(xs, bi.z, w.z);
        r.w = fmaf(xs, bi.w, w.w);
        __builtin_nontemporal_store(r, &out4[i]);
    }
}

extern "C" void kernel_launch(void* const* d_in, const int* in_sizes, int n_in,
                              void* d_out, int out_size, void* d_ws, size_t ws_size,
                              hipStream_t stream) {
    const float* input  = (const float*)d_in[0];
    const float* weight = (const float*)d_in[1];
    const float* bias   = (const float*)d_in[2];
    float* out = (float*)d_out;
    float* wb  = (float*)d_ws;   // 4096 floats: bias[o] * w_sum[o]

    wsum_kernel<<<OUT_DIM / 4, 256, 0, stream>>>(weight, bias, wb);
    fused_kernel<<<B_DIM, 256, 0, stream>>>(input, bias, wb, out);
}